// Round 1
// baseline (151.840 us; speedup 1.0000x reference)
//
#include <hip/hip_runtime.h>
#include <math.h>

// Problem constants
#define BATCH 8192
#define LOD 60
#define LSD 120
#define AD 10
#define NB 15
#define BW 3
#define H 60

// Output layout (floats)
#define NM_SZ (BATCH * LSD)   // next_mean 983040
#define NC_SZ (BATCH * LOD)   // 491520 each for ncu/ncl/ncs

// LDS overlay region layout (floats)
#define VSJ 65
#define VSV (18 * VSJ)          // 1170 floats per staged tensor plane
#define VS_FLOATS 5856          // 5*VSV = 5850, padded to 16B multiple
#define PACK_FLOATS 5040        // 12 rows * 15 k * 7 jo * 4 m
#define OVL_FLOATS (VS_FLOATS + PACK_FLOATS)   // 10896 floats = 43.6 KB
// phase-1 usage of the same region: pm_s [120][65] = 7800 @ ovl+0,
//                                   act_s [10][65] = 650  @ ovl+7800  (8450 <= 10896)

__device__ __forceinline__ float elup1f(float x) {
    return x < 0.0f ? __expf(x) : x + 1.0f;
}

// ---------------------------------------------------------------------------
// Single fused kernel. Grid: 128 batch-groups x 5 row-groups, block 256 = 4 waves.
// Phase 1 (per block, redundant across the 5 row-groups — cheap):
//   - stage pm tile transposed [j][b] + action transposed [a][b] in LDS
//   - logits (each wave owns 4 of the 15 k-rows) -> softmax in place -> coef_s[k][b]
//   - control MLP: each wave computes 6 of the 24 needed output rows -> ctrl_s[oo][b]
// Phase 2 (same as previous k2, but tm pack staged into LDS instead of workspace):
//   - vs staging (5 tensors x 18 cols), pack_s staging (12 rows of banded tm)
//   - per-wave mixing + banded products, outputs kept in registers
//   - ost staging (overlays pack_s after a barrier) -> coalesced float4 flush
// ---------------------------------------------------------------------------
__global__ __launch_bounds__(256, 3) void k_fused(
    const float* __restrict__ pm, const float* __restrict__ cu,
    const float* __restrict__ cl, const float* __restrict__ cs,
    const float* __restrict__ action,
    const float* __restrict__ tm11, const float* __restrict__ tm12,
    const float* __restrict__ tm21, const float* __restrict__ tm22,
    const float* __restrict__ log_noise,
    const float* __restrict__ w_coef, const float* __restrict__ b_coef,
    const float* __restrict__ w_c1, const float* __restrict__ b_c1,
    const float* __restrict__ w_c2, const float* __restrict__ b_c2,
    float* __restrict__ out)
{
    __shared__ float coef_s[NB * 65];          // [k][b] softmax coefs (3.9 KB)
    __shared__ float ctrl_s[24 * 65];          // [oo][b] control rows (6.2 KB)
    __shared__ __align__(16) float ovl[OVL_FLOATS];  // overlaid region (43.6 KB)

    const int tid  = threadIdx.x;
    const int wave = tid >> 6;
    const int lane = tid & 63;
    const int bg = blockIdx.x / 5;   // batch group
    const int rg = blockIdx.x % 5;   // row group
    const int b0 = bg * 64;
    const int i0 = rg * 12;

    // ---------------- phase 1 ----------------
    float* pm_s  = ovl;            // [j][b], j<120, stride 65
    float* act_s = ovl + 7800;     // [a][b], a<10,  stride 65

    for (int idx = tid; idx < 64 * LSD; idx += 256) {
        int b = idx / LSD, j = idx % LSD;            // consecutive tid -> coalesced global
        pm_s[j * 65 + b] = pm[(b0 + b) * LSD + j];
    }
    for (int idx = tid; idx < 64 * AD; idx += 256) {
        int b = idx / AD, a = idx % AD;
        act_s[a * 65 + b] = action[(b0 + b) * AD + a];
    }
    __syncthreads();

    // logits: wave w owns k in {w, w+4, w+8, w+12}; k=15 slot is a discarded dummy
    {
        const int k3 = (wave < 3) ? wave + 12 : 14;
        float a0 = b_coef[wave], a1 = b_coef[wave + 4], a2 = b_coef[wave + 8];
        float a3 = b_coef[k3];
        for (int j = 0; j < LSD; ++j) {
            float p = pm_s[j * 65 + lane];           // conflict-free (stride-1 lanes)
            a0 = fmaf(p, w_coef[(wave    ) * LSD + j], a0);  // wave-uniform weight loads
            a1 = fmaf(p, w_coef[(wave + 4) * LSD + j], a1);
            a2 = fmaf(p, w_coef[(wave + 8) * LSD + j], a2);
            a3 = fmaf(p, w_coef[k3 * LSD + j], a3);
        }
        coef_s[wave * 65 + lane] = a0;
        coef_s[(wave + 4) * 65 + lane] = a1;
        coef_s[(wave + 8) * 65 + lane] = a2;
        if (wave < 3) coef_s[k3 * 65 + lane] = a3;
    }
    __syncthreads();

    // control MLP: wave handles 6 of the 24 needed output rows for batch = lane;
    // hidden layer recomputed per wave (600 FMA) to avoid an LDS hid buffer.
    {
        int o_[6];
        #pragma unroll
        for (int z = 0; z < 6; ++z) {
            int oo = wave * 6 + z;
            o_[z] = (oo < 12) ? (i0 + oo) : (48 + i0 + oo);  // 60 + i0 + (oo-12)
        }
        float av[AD];
        #pragma unroll
        for (int a = 0; a < AD; ++a) av[a] = act_s[a * 65 + lane];
        float acc[6];
        #pragma unroll
        for (int z = 0; z < 6; ++z) acc[z] = 0.0f;
        for (int h = 0; h < H; ++h) {
            float hv = b_c1[h];
            #pragma unroll
            for (int a = 0; a < AD; ++a) hv = fmaf(av[a], w_c1[h * AD + a], hv);
            hv = fmaxf(hv, 0.0f);
            #pragma unroll
            for (int z = 0; z < 6; ++z)
                acc[z] = fmaf(hv, w_c2[o_[z] * H + h], acc[z]);
        }
        #pragma unroll
        for (int z = 0; z < 6; ++z)
            ctrl_s[(wave * 6 + z) * 65 + lane] = acc[z] + b_c2[o_[z]];
    }

    // softmax normalize coef_s in place (threads 0..63; batch = tid; stride-65
    // column reads are conflict-free). Runs while waves 1-3 finish the MLP.
    if (tid < 64) {
        float v[NB];
        float mx = -1e30f;
        #pragma unroll
        for (int k = 0; k < NB; ++k) { v[k] = coef_s[k * 65 + tid]; mx = fmaxf(mx, v[k]); }
        float sm = 0.0f;
        #pragma unroll
        for (int k = 0; k < NB; ++k) { v[k] = __expf(v[k] - mx); sm += v[k]; }
        float inv = 1.0f / sm;
        #pragma unroll
        for (int k = 0; k < NB; ++k) coef_s[k * 65 + tid] = v[k] * inv;
    }
    __syncthreads();   // phase-1 reads of ovl done; coef_s/ctrl_s final

    // ---------------- phase 2 ----------------
    float* vs     = ovl;                // [v][jj][b], 5 tensors, stride 65
    float* pack_s = ovl + VS_FLOATS;    // [ri][k][jo][m], float4 over m

    // vs staging: jj fastest -> 72B contiguous global runs (pm tile is L2-hot)
    for (int idx = tid; idx < 5 * 64 * 18; idx += 256) {
        int v   = idx / (64 * 18);
        int rem = idx - v * (64 * 18);
        int blc = rem / 18;
        int jj  = rem - blc * 18;
        int j   = i0 - BW + jj;
        int bb  = b0 + blc;
        float val = 0.0f;
        if (j >= 0 && j < LOD) {
            if (v == 0)      val = pm[bb * LSD + j];
            else if (v == 1) val = pm[bb * LSD + LOD + j];
            else if (v == 2) val = cu[bb * LOD + j];
            else if (v == 3) val = cl[bb * LOD + j];
            else             val = cs[bb * LOD + j];
        }
        vs[v * VSV + jj * VSJ + blc] = val;
    }
    // banded tm pack into LDS: jo fastest -> 28B contiguous global runs (L2/L3-hot)
    for (int idx = tid; idx < PACK_FLOATS; idx += 256) {
        int jo = idx % 7;
        int t2 = idx / 7;
        int ri = t2 % 12;
        int t3 = t2 / 12;
        int k  = t3 % 15;
        int m  = t3 / 15;
        int i  = i0 + ri;
        int j  = i - BW + jo;
        const float* tmm = (m == 0) ? tm11 : (m == 1) ? tm12 : (m == 2) ? tm21 : tm22;
        float val = (j >= 0 && j < LOD) ? tmm[k * (LOD * LOD) + i * LOD + j] : 0.0f;
        pack_s[((ri * NB + k) * 7 + jo) * 4 + m] = val;
    }

    // per-lane coef from LDS (written before the last barrier)
    float cf[NB];
    #pragma unroll
    for (int k = 0; k < NB; ++k) cf[k] = coef_s[k * 65 + lane];

    __syncthreads();

    float onm[3], onl[3], ou[3], olv[3], osv[3];
    #pragma unroll
    for (int rr = 0; rr < 3; ++rr) {
        const int riu = __builtin_amdgcn_readfirstlane(wave * 3 + rr);  // wave-uniform row
        const int iu  = i0 + riu;

        // ---- mixing: t[jo*4+m] = sum_k cf[k] * pack[ri][k][jo][m] ----
        float t[28];
        #pragma unroll
        for (int z = 0; z < 28; ++z) t[z] = 0.0f;

        const float4* tp = (const float4*)pack_s + riu * (NB * 7);
        #pragma unroll
        for (int k = 0; k < NB; ++k) {
            float c = cf[k];
            #pragma unroll
            for (int jo = 0; jo < 7; ++jo) {
                float4 tv = tp[k * 7 + jo];          // uniform addr -> LDS broadcast
                t[jo * 4 + 0] = fmaf(c, tv.x, t[jo * 4 + 0]);
                t[jo * 4 + 1] = fmaf(c, tv.y, t[jo * 4 + 1]);
                t[jo * 4 + 2] = fmaf(c, tv.z, t[jo * 4 + 2]);
                t[jo * 4 + 3] = fmaf(c, tv.w, t[jo * 4 + 3]);
            }
        }
        t[3 * 4 + 0] += 1.0f;   // + eye on t11 at j == i
        t[3 * 4 + 3] += 1.0f;   // + eye on t22 at j == i

        // ---- banded products ----
        float nmu = 0.f, nml = 0.f, ncuv = 0.f, nclv = 0.f, ncsv = 0.f;
        #pragma unroll
        for (int jo = 0; jo < 7; ++jo) {
            const int jj = riu + jo;
            float m_ = vs[0 * VSV + jj * VSJ + lane];
            float n_ = vs[1 * VSV + jj * VSJ + lane];
            float u_ = vs[2 * VSV + jj * VSJ + lane];
            float l_ = vs[3 * VSV + jj * VSJ + lane];
            float s_ = vs[4 * VSV + jj * VSJ + lane];
            float A = t[jo * 4 + 0], Bv = t[jo * 4 + 1];
            float C = t[jo * 4 + 2], D  = t[jo * 4 + 3];
            nmu = fmaf(A, m_, nmu);  nmu = fmaf(Bv, n_, nmu);
            nml = fmaf(C, m_, nml);  nml = fmaf(D, n_, nml);
            float e1 = fmaf(Bv, s_, A * u_);   // A*u + B*s
            float e2 = fmaf(Bv, l_, A * s_);   // A*s + B*l
            float f1 = fmaf(D, s_, C * u_);    // C*u + D*s
            float f2 = fmaf(D, l_, C * s_);    // C*s + D*l
            ncuv = fmaf(A, e1, ncuv);  ncuv = fmaf(Bv, e2, ncuv);
            nclv = fmaf(C, f1, nclv);  nclv = fmaf(D, f2, nclv);
            ncsv = fmaf(C, e1, ncsv);  ncsv = fmaf(D, e2, ncsv);
        }

        // trans_cov + control
        ncuv += elup1f(log_noise[iu]);
        nclv += elup1f(log_noise[LOD + iu]);
        nmu  += ctrl_s[riu * 65 + lane];
        nml  += ctrl_s[(12 + riu) * 65 + lane];

        onm[rr] = nmu; onl[rr] = nml; ou[rr] = ncuv; olv[rr] = nclv; osv[rr] = ncsv;
    }
    __syncthreads();   // all waves done reading pack_s/vs

    // output staging overlays the pack region: [t][ri][b], stride 65
    float* ost = ovl + VS_FLOATS;
    #pragma unroll
    for (int rr = 0; rr < 3; ++rr) {
        int ri = wave * 3 + rr;
        ost[0 * 780 + ri * 65 + lane] = onm[rr];
        ost[1 * 780 + ri * 65 + lane] = onl[rr];
        ost[2 * 780 + ri * 65 + lane] = ou[rr];
        ost[3 * 780 + ri * 65 + lane] = olv[rr];
        ost[4 * 780 + ri * 65 + lane] = osv[rr];
    }
    __syncthreads();

    // coalesced float4 output flush (i0 % 4 == 0 -> 16B-aligned bases)
    for (int idx = tid; idx < 5 * 64 * 3; idx += 256) {
        int t5  = idx / 192;
        int rem = idx - t5 * 192;
        int blc = rem / 3;
        int qq  = rem - blc * 3;
        int bb  = b0 + blc;
        int ri0 = qq * 4;
        float4 v;
        v.x = ost[t5 * 780 + (ri0 + 0) * 65 + blc];
        v.y = ost[t5 * 780 + (ri0 + 1) * 65 + blc];
        v.z = ost[t5 * 780 + (ri0 + 2) * 65 + blc];
        v.w = ost[t5 * 780 + (ri0 + 3) * 65 + blc];
        float* bp;
        if (t5 == 0)      bp = out + bb * LSD + i0;
        else if (t5 == 1) bp = out + bb * LSD + LOD + i0;
        else if (t5 == 2) bp = out + NM_SZ + bb * LOD + i0;
        else if (t5 == 3) bp = out + NM_SZ + NC_SZ + bb * LOD + i0;
        else              bp = out + NM_SZ + 2 * NC_SZ + bb * LOD + i0;
        *(float4*)(bp + ri0) = v;
    }
}

extern "C" void kernel_launch(void* const* d_in, const int* in_sizes, int n_in,
                              void* d_out, int out_size, void* d_ws, size_t ws_size,
                              hipStream_t stream) {
    (void)in_sizes; (void)n_in; (void)out_size; (void)d_ws; (void)ws_size;
    const float* pm        = (const float*)d_in[0];
    const float* cu        = (const float*)d_in[1];
    const float* cl        = (const float*)d_in[2];
    const float* cs        = (const float*)d_in[3];
    const float* action    = (const float*)d_in[4];
    const float* tm11      = (const float*)d_in[5];
    const float* tm12      = (const float*)d_in[6];
    const float* tm21      = (const float*)d_in[7];
    const float* tm22      = (const float*)d_in[8];
    const float* log_noise = (const float*)d_in[9];
    const float* w_coef    = (const float*)d_in[10];
    const float* b_coef    = (const float*)d_in[11];
    const float* w_c1      = (const float*)d_in[12];
    const float* b_c1      = (const float*)d_in[13];
    const float* w_c2      = (const float*)d_in[14];
    const float* b_c2      = (const float*)d_in[15];

    hipLaunchKernelGGL(k_fused, dim3(128 * 5), dim3(256), 0, stream,
                       pm, cu, cl, cs, action, tm11, tm12, tm21, tm22,
                       log_noise, w_coef, b_coef, w_c1, b_c1, w_c2, b_c2,
                       (float*)d_out);
}